// Round 11
// baseline (96.019 us; speedup 1.0000x reference)
//
#include <hip/hip_runtime.h>
#include <hip/hip_bf16.h>
#include <math.h>

// TokenCompressor: B=8, N=16384, C=128, BLOCK=32, STRIDE=16 -> nb=1023
// Decomposition: chunks c of 16 tokens; A = x.view(8192, 2048) (contiguous!)
//   P[m, 0:256]  = chunk[m] @ W1[0:2048]
//   P[m, 256:512]= chunk[m] @ W1[2048:4096]
//   h[j] = gelu(P[j,0:256] + P[j+1,256:512] + b1 + posflat@W1)
//   out[j] = h[j] @ W2 + b2
// R11: R1-R10 all sat at the m102-measured 2048-equivalent wall (~320 TF)
// of barrier-per-K-step structures. Fix: decouple A from barriers --
// A goes global->register directly (f32 dwordx4 pairs + cvt_pk, 1-step
// software pipeline, no LDS/xcvt/splitK); only B (L2-resident 2MB) is LDS-
// staged, in K=128 chunks (4 steps/chunk) -> 16 barrier-pairs per block
// instead of 64, exact vmcnt(8) bookkeeping at chunk seams. Grid 256
// (1/CU), 8 waves 4mx2n, per-wave 32x64 acc[2][4], full K=2048 (64 steps).

typedef __attribute__((ext_vector_type(8))) short short8;
typedef __attribute__((ext_vector_type(4))) float f4;

#define OFF_BT   0u                          // 512x2048 bf16 = 2 MB
#define OFF_W2T  (2u << 20)                  // 128x256 bf16 = 64 KB
#define OFF_PART ((2u << 20) + (64u << 10))  // 64x256 f32 = 64 KB
#define OFF_BIAS ((2u << 20) + (128u << 10)) // 256 f32
#define OFF_P    (4u << 20)                  // 8192x512 bf16 = 8 MB

static __device__ __forceinline__ unsigned short f2bf(float f) {
  union { float f; unsigned u; } v; v.f = f;
  return (unsigned short)((v.u + 0x7FFFu + ((v.u >> 16) & 1u)) >> 16);
}
static __device__ __forceinline__ float bf2f(unsigned short h) {
  union { unsigned u; float f; } v; v.u = ((unsigned)h) << 16;
  return v.f;
}
static __device__ __forceinline__ void gload_lds16(const void* g, void* l) {
  __builtin_amdgcn_global_load_lds(
      (const __attribute__((address_space(1))) void*)g,
      (__attribute__((address_space(3))) void*)l, 16, 0, 0);
}

// ---- k_prep: blocks 0..255: W1 -> Bt (512x2048 bf16, n-major) + bias parts
//              blocks 256..383: W2 (256x128 f32) -> W2t (128x256 bf16, T)
__global__ __launch_bounds__(256) void k_prep(const float* __restrict__ W1,
                                              const float* __restrict__ pos,
                                              const float* __restrict__ W2,
                                              unsigned short* __restrict__ Bt,
                                              unsigned short* __restrict__ W2t,
                                              float* __restrict__ part) {
  __shared__ float T[64][65];
  const int w = blockIdx.x;
  const int t = threadIdx.x;
  if (w >= 256) {
    const int n = w - 256;
    W2t[n * 256 + t] = f2bf(W2[t * 128 + n]);
    return;
  }
  const int h = w >> 7, rem = w & 127, kt = rem >> 2, nt = rem & 3;
  const int krow0 = h * 2048 + kt * 64, col0 = nt * 64;
  const int lr = t >> 2, lc = (t & 3) * 16;
  const float* src = W1 + (size_t)(krow0 + lr) * 256 + col0 + lc;
#pragma unroll
  for (int i = 0; i < 4; ++i) {
    f4 v = *(const f4*)(src + i * 4);
#pragma unroll
    for (int q = 0; q < 4; ++q) T[lr][lc + i * 4 + q] = v[q];
  }
  __syncthreads();
  if (t < 64) {
    float s = 0.f;
#pragma unroll 8
    for (int k = 0; k < 64; ++k) s += T[k][t] * pos[krow0 + k];
    part[(h * 32 + kt) * 256 + col0 + t] = s;
  }
  const int nl = t >> 2, kc = (t & 3) * 16;
  short8 o0, o1;
#pragma unroll
  for (int i = 0; i < 8; ++i) o0[i] = (short)f2bf(T[kc + i][nl]);
#pragma unroll
  for (int i = 0; i < 8; ++i) o1[i] = (short)f2bf(T[kc + 8 + i][nl]);
  unsigned short* dst = Bt + (size_t)(256 * h + col0 + nl) * 2048 + kt * 64 + kc;
  *(short8*)dst = o0;
  *(short8*)(dst + 8) = o1;
}

// ---- k_bias ------------------------------------------------------------
__global__ __launch_bounds__(256) void k_bias(const float* __restrict__ b1,
                                              const float* __restrict__ part,
                                              float* __restrict__ bias) {
  int n = threadIdx.x;
  float s = b1[n];
#pragma unroll 8
  for (int g = 0; g < 64; ++g) s += part[g * 256 + n];
  bias[n] = s;
}

// ---- k_gemm: P (8192x512 bf16) = X(f32) @ Bt^T, full K=2048 -------------
// Grid 256 = 64mt x 4nt (XCD-swizzled: each XCD owns 8 consecutive mt).
// 512 thr = 8 waves (4m x 2n): wave = rows wr*32..+31, cols wc*64..+63,
// acc[2][4]. A: global->reg f32 (2 dwordx4/frag) + cvt_pk, 1-step pipeline,
// NO LDS/barriers. B: LDS chunks [128n][128k] bf16 (32KB x2), 16B chunk
// swizzle c ^= row&15 (pre-swizzled DMA source), barriers only at chunk
// seams (16x), exact counted vmcnt(8).
__global__ __launch_bounds__(512) void k_gemm(const float* __restrict__ X,
                                              const unsigned short* __restrict__ Bt,
                                              unsigned short* __restrict__ P) {
  __shared__ __align__(16) unsigned short Bl[2][128 * 128];  // 32 KB each
  const int orig = blockIdx.x;
  const int wg = (orig & 7) * 32 + (orig >> 3);  // bijective (256%8==0)
  const int mt = wg >> 2, nt = wg & 3;   // XCD x: mt in [x*8, x*8+8)
  const int m0 = mt * 128, n0 = nt * 128;
  const int t = threadIdx.x;
  const int wid = t >> 6, lane = t & 63;
  const int wr = wid >> 1, wc = wid & 1;
  const float* Abase =
      X + (size_t)(m0 + wr * 32 + (lane & 15)) * 2048 + (lane >> 4) * 8;

  f4 acc[2][4];
#pragma unroll
  for (int m = 0; m < 2; ++m)
#pragma unroll
    for (int n = 0; n < 4; ++n) acc[m][n] = f4{0.f, 0.f, 0.f, 0.f};

  f4 a0[2][2], a1[2][2];  // [frag][lo/hi] f32, double-buffered across steps

#define LOADA(DST, KCOL)                                                   \
  do {                                                                     \
    _Pragma("unroll") for (int f = 0; f < 2; ++f) {                        \
      DST[f][0] = *(const f4*)(Abase + f * 32768 + (KCOL));                \
      DST[f][1] = *(const f4*)(Abase + f * 32768 + (KCOL) + 4);            \
    }                                                                      \
  } while (0)

  // B DMA, one chunk = 32KB: 4 instr/thread. slot s=ii*512+t: row=s>>4,
  // c16=s&15; source chunk = c16 ^ (row&15); LDS dest linear.
#define ISSUE_B(BUF, CI)                                                   \
  do {                                                                     \
    _Pragma("unroll") for (int ii = 0; ii < 4; ++ii) {                     \
      const int s = ii * 512 + t;                                          \
      const int row = s >> 4, c16 = s & 15;                                \
      gload_lds16(Bt + (size_t)(n0 + row) * 2048 + (CI) * 128 +            \
                      ((c16 ^ (row & 15)) << 3),                           \
                  (char*)&Bl[BUF][0] + ii * 8192 + wid * 1024);            \
    }                                                                      \
  } while (0)

  // one 32-K step: cvt A regs -> bf16 frags, read 4 B frags, 8 MFMA.
#define COMPUTE(BUF, S, ASRC)                                              \
  do {                                                                     \
    short8 af[2], bf[4];                                                   \
    _Pragma("unroll") for (int f = 0; f < 2; ++f) {                        \
      union { short8 s8; unsigned u[4]; } pk;                              \
      asm("v_cvt_pk_bf16_f32 %0, %1, %2" : "=v"(pk.u[0])                   \
          : "v"(ASRC[f][0][0]), "v"(ASRC[f][0][1]));                       \
      asm("v_cvt_pk_bf16_f32 %0, %1, %2" : "=v"(pk.u[1])                   \
          : "v"(ASRC[f][0][2]), "v"(ASRC[f][0][3]));                       \
      asm("v_cvt_pk_bf16_f32 %0, %1, %2" : "=v"(pk.u[2])                   \
          : "v"(ASRC[f][1][0]), "v"(ASRC[f][1][1]));                       \
      asm("v_cvt_pk_bf16_f32 %0, %1, %2" : "=v"(pk.u[3])                   \
          : "v"(ASRC[f][1][2]), "v"(ASRC[f][1][3]));                       \
      af[f] = pk.s8;                                                       \
    }                                                                      \
    _Pragma("unroll") for (int j = 0; j < 4; ++j) {                        \
      const int row = wc * 64 + j * 16 + (lane & 15);                      \
      const int c16 = (S) * 4 + (lane >> 4);                               \
      bf[j] = *(const short8*)&Bl[BUF][row * 128 +                         \
                                       ((c16 ^ (row & 15)) << 3)];         \
    }                                                                      \
    __builtin_amdgcn_s_setprio(1);                                         \
    _Pragma("unroll") for (int f = 0; f < 2; ++f)                          \
      _Pragma("unroll") for (int j = 0; j < 4; ++j)                        \
        acc[f][j] = __builtin_amdgcn_mfma_f32_16x16x32_bf16(               \
            af[f], bf[j], acc[f][j], 0, 0, 0);                             \
    __builtin_amdgcn_s_setprio(0);                                         \
  } while (0)

  // prologue: A(step0) + B chunks 0,1 in flight; wait A + B0 (vmcnt(4)).
  LOADA(a0, 0);
  ISSUE_B(0, 0);
  ISSUE_B(1, 1);
  __builtin_amdgcn_sched_barrier(0);
  asm volatile("s_waitcnt vmcnt(4)" ::: "memory");
  __builtin_amdgcn_s_barrier();
  __builtin_amdgcn_sched_barrier(0);

  for (int ci = 0; ci < 16; ++ci) {
    const int buf = ci & 1;
    const int ck = ci * 128;
    // s0..s3, A pipelined one step ahead (crosses chunk seam freely)
    LOADA(a1, ck + 32);
    COMPUTE(buf, 0, a0);
    LOADA(a0, ck + 64);
    COMPUTE(buf, 1, a1);
    LOADA(a1, ck + 96);
    COMPUTE(buf, 2, a0);
    if (ci < 15) LOADA(a0, ck + 128);  // next chunk's s0
    COMPUTE(buf, 3, a1);
    if (ci == 15) break;
    __builtin_amdgcn_sched_barrier(0);
    __builtin_amdgcn_s_barrier();  // all waves done reading Bl[buf]
    __builtin_amdgcn_sched_barrier(0);
    if (ci < 14) {
      ISSUE_B(buf, ci + 2);
      __builtin_amdgcn_sched_barrier(0);
      // outstanding: A(next s0) x4 + B(ci+2) x4 = 8 newest; older B(ci+1)
      // must have landed.
      asm volatile("s_waitcnt vmcnt(8)" ::: "memory");
    } else {
      __builtin_amdgcn_sched_barrier(0);
      asm volatile("s_waitcnt vmcnt(4)" ::: "memory");  // B(15) landed
    }
    __builtin_amdgcn_s_barrier();
    __builtin_amdgcn_sched_barrier(0);
  }
#undef LOADA
#undef ISSUE_B
#undef COMPUTE

  // epilogue: P bf16. C/D layout: col=lane&15, row=(lane>>4)*4+reg
  const int mb = m0 + wr * 32, nb = n0 + wc * 64;
#pragma unroll
  for (int m = 0; m < 2; ++m)
#pragma unroll
    for (int n = 0; n < 4; ++n) {
      const int row0 = mb + m * 16 + ((lane >> 4) << 2);
      const int col = nb + n * 16 + (lane & 15);
#pragma unroll
      for (int r = 0; r < 4; ++r)
        P[(size_t)(row0 + r) * 512 + col] = f2bf(acc[m][n][r]);
    }
}

// ---- k_comb: h=gelu(P0+P1+bias); out = h@W2 + b2 -----------------------
__global__ __launch_bounds__(256) void k_comb(const unsigned short* __restrict__ P,
                                              const unsigned short* __restrict__ W2t,
                                              const float* __restrict__ bias,
                                              const float* __restrict__ b2,
                                              float* __restrict__ out) {
  __shared__ unsigned short W2s[128 * 256];
  __shared__ unsigned short Hs[32 * 256];
  const int wg = blockIdx.x;
  const int b = wg >> 5, jt = wg & 31;
  const int j0 = jt * 32;
  const int t = threadIdx.x;

  {  // stage W2t (rows 512B; swizzle slot ^= row&7)
    const int row = t >> 1, halfc = (t & 1) * 128;
    const unsigned short* src = W2t + row * 256 + halfc;
    const int cbw = halfc >> 3;
#pragma unroll
    for (int i = 0; i < 16; ++i) {
      short8 v = *(const short8*)(src + i * 8);
      const int c = (cbw + i) ^ (row & 7);
      *(short8*)&W2s[row * 256 + c * 8] = v;
    }
  }
  {  // h rows: thread = (row r, 32-col segment)
    const int r = t >> 3, seg = t & 7;
    const int j = j0 + r;
    const size_t m = (size_t)b * 1024 + j;
    const size_t mp1 = (j < 1023) ? m + 1 : m;  // clamp (masked later)
    const unsigned short* p0 = P + m * 512 + seg * 32;
    const unsigned short* p1 = P + mp1 * 512 + 256 + seg * 32;
    const float* bs = bias + seg * 32;
    const int cbh = seg * 4;
#pragma unroll
    for (int i = 0; i < 4; ++i) {
      short8 v0 = *(const short8*)(p0 + i * 8);
      short8 v1 = *(const short8*)(p1 + i * 8);
      short8 pk;
#pragma unroll
      for (int q = 0; q < 8; ++q) {
        float f = bf2f((unsigned short)v0[q]) + bf2f((unsigned short)v1[q]) +
                  bs[i * 8 + q];
        float g = 0.5f * f * (1.f + erff(f * 0.70710678118f));
        pk[q] = (short)f2bf(g);
      }
      const int c = (cbh + i) ^ (r & 7);
      *(short8*)&Hs[r * 256 + c * 8] = pk;
    }
  }
  __syncthreads();

  const int wid = t >> 6, lane = t & 63;
  f4 acc[2][2];
#pragma unroll
  for (int i = 0; i < 2; ++i)
#pragma unroll
    for (int j = 0; j < 2; ++j) acc[i][j] = f4{0.f, 0.f, 0.f, 0.f};

#pragma unroll
  for (int ks = 0; ks < 8; ++ks) {
    short8 af[2], bfr[2];
    const int cc = ks * 4 + (lane >> 4);
#pragma unroll
    for (int f = 0; f < 2; ++f) {
      const int ra = f * 16 + (lane & 15);
      af[f] = *(const short8*)&Hs[ra * 256 + ((cc ^ (ra & 7)) << 3)];
      const int rb = wid * 32 + f * 16 + (lane & 15);
      bfr[f] = *(const short8*)&W2s[rb * 256 + ((cc ^ (rb & 7)) << 3)];
    }
#pragma unroll
    for (int i = 0; i < 2; ++i)
#pragma unroll
      for (int j = 0; j < 2; ++j)
        acc[i][j] = __builtin_amdgcn_mfma_f32_16x16x32_bf16(af[i], bfr[j],
                                                            acc[i][j], 0, 0, 0);
  }
#pragma unroll
  for (int i = 0; i < 2; ++i)
#pragma unroll
    for (int j = 0; j < 2; ++j) {
      const int row0 = i * 16 + ((lane >> 4) << 2);
      const int col = wid * 32 + j * 16 + (lane & 15);
      const float bb = b2[col];
#pragma unroll
      for (int r = 0; r < 4; ++r) {
        const int jj = j0 + row0 + r;
        if (jj < 1023)
          out[((size_t)b * 1023 + jj) * 128 + col] = acc[i][j][r] + bb;
      }
    }
}

extern "C" void kernel_launch(void* const* d_in, const int* in_sizes, int n_in,
                              void* d_out, int out_size, void* d_ws, size_t ws_size,
                              hipStream_t stream) {
  const float* x   = (const float*)d_in[0];
  const float* pos = (const float*)d_in[1];
  const float* W1  = (const float*)d_in[2];
  const float* b1  = (const float*)d_in[3];
  const float* W2  = (const float*)d_in[4];
  const float* b2  = (const float*)d_in[5];
  float* out = (float*)d_out;
  char* ws = (char*)d_ws;
  unsigned short* Bt  = (unsigned short*)(ws + OFF_BT);
  unsigned short* W2t = (unsigned short*)(ws + OFF_W2T);
  float* part         = (float*)(ws + OFF_PART);
  float* bias         = (float*)(ws + OFF_BIAS);
  unsigned short* P   = (unsigned short*)(ws + OFF_P);

  k_prep<<<384, 256, 0, stream>>>(W1, pos, W2, Bt, W2t, part);
  k_bias<<<1, 256, 0, stream>>>(b1, part, bias);
  k_gemm<<<256, 512, 0, stream>>>(x, Bt, P);
  k_comb<<<256, 256, 0, stream>>>(P, W2t, bias, b2, out);
}

// Round 12
// 58.619 us; speedup vs baseline: 1.6380x; 1.6380x over previous
//
#include <hip/hip_runtime.h>
#include <hip/hip_bf16.h>
#include <math.h>

// TokenCompressor: B=8, N=16384, C=128, BLOCK=32, STRIDE=16 -> nb=1023
// Decomposition: chunks c of 16 tokens; A = x.view(8192, 2048) (contiguous!)
//   P[m, 0:256]  = chunk[m] @ W1[0:2048]
//   P[m, 256:512]= chunk[m] @ W1[2048:4096]
//   h[j] = gelu(P[j,0:256] + P[j+1,256:512] + b1 + posflat@W1)
//   out[j] = h[j] @ W2 + b2
// R12: R9 chassis (gload_lds f32-A + bf16-B, counted vmcnt -- the only
// staging the compiler can't sink; R3/R5/R11 proved reg-prefetch dies) with
// 2x better LDS-read:MFMA ratio: 256x256 block, 8 waves 4m x 2n, per-wave
// 64x128 acc[4][8] -> 0.5 reads/MFMA (R9 was 1.0), BK=32, 16 steps (half
// the barriers). split-K=4 -> grid 256 (1/CU). LDS 96KB. 4 bf16 partials.

typedef __attribute__((ext_vector_type(8))) short short8;
typedef __attribute__((ext_vector_type(4))) float f4;

#define OFF_BT   0u                          // 512x2048 bf16 = 2 MB
#define OFF_W2T  (2u << 20)                  // 128x256 bf16 = 64 KB
#define OFF_PART ((2u << 20) + (64u << 10))  // 64x256 f32 = 64 KB
#define OFF_BIAS ((2u << 20) + (128u << 10)) // 256 f32
#define OFF_P    (4u << 20)                  // 4 x (8192x512) bf16 = 32 MB

static __device__ __forceinline__ unsigned short f2bf(float f) {
  union { float f; unsigned u; } v; v.f = f;
  return (unsigned short)((v.u + 0x7FFFu + ((v.u >> 16) & 1u)) >> 16);
}
static __device__ __forceinline__ float bf2f(unsigned short h) {
  union { unsigned u; float f; } v; v.u = ((unsigned)h) << 16;
  return v.f;
}
static __device__ __forceinline__ void gload_lds16(const void* g, void* l) {
  __builtin_amdgcn_global_load_lds(
      (const __attribute__((address_space(1))) void*)g,
      (__attribute__((address_space(3))) void*)l, 16, 0, 0);
}

// ---- k_prep: blocks 0..255: W1 -> Bt (512x2048 bf16, n-major) + bias parts
//              blocks 256..383: W2 (256x128 f32) -> W2t (128x256 bf16, T)
__global__ __launch_bounds__(256) void k_prep(const float* __restrict__ W1,
                                              const float* __restrict__ pos,
                                              const float* __restrict__ W2,
                                              unsigned short* __restrict__ Bt,
                                              unsigned short* __restrict__ W2t,
                                              float* __restrict__ part) {
  __shared__ float T[64][65];
  const int w = blockIdx.x;
  const int t = threadIdx.x;
  if (w >= 256) {
    const int n = w - 256;
    W2t[n * 256 + t] = f2bf(W2[t * 128 + n]);
    return;
  }
  const int h = w >> 7, rem = w & 127, kt = rem >> 2, nt = rem & 3;
  const int krow0 = h * 2048 + kt * 64, col0 = nt * 64;
  const int lr = t >> 2, lc = (t & 3) * 16;
  const float* src = W1 + (size_t)(krow0 + lr) * 256 + col0 + lc;
#pragma unroll
  for (int i = 0; i < 4; ++i) {
    f4 v = *(const f4*)(src + i * 4);
#pragma unroll
    for (int q = 0; q < 4; ++q) T[lr][lc + i * 4 + q] = v[q];
  }
  __syncthreads();
  if (t < 64) {
    float s = 0.f;
#pragma unroll 8
    for (int k = 0; k < 64; ++k) s += T[k][t] * pos[krow0 + k];
    part[(h * 32 + kt) * 256 + col0 + t] = s;
  }
  const int nl = t >> 2, kc = (t & 3) * 16;
  short8 o0, o1;
#pragma unroll
  for (int i = 0; i < 8; ++i) o0[i] = (short)f2bf(T[kc + i][nl]);
#pragma unroll
  for (int i = 0; i < 8; ++i) o1[i] = (short)f2bf(T[kc + 8 + i][nl]);
  unsigned short* dst = Bt + (size_t)(256 * h + col0 + nl) * 2048 + kt * 64 + kc;
  *(short8*)dst = o0;
  *(short8*)(dst + 8) = o1;
}

// ---- k_bias ------------------------------------------------------------
__global__ __launch_bounds__(256) void k_bias(const float* __restrict__ b1,
                                              const float* __restrict__ part,
                                              float* __restrict__ bias) {
  int n = threadIdx.x;
  float s = b1[n];
#pragma unroll 8
  for (int g = 0; g < 64; ++g) s += part[g * 256 + n];
  bias[n] = s;
}

// ---- k_gemm: Ppart[ksp] (8192x512 bf16) = X(f32)[:,ksp*512:+512] @ Bt^T --
// 256x256 block, BK=32, 16 steps. 512 thr = 8 waves (4m x 2n): wave =
// rows wr*64..+63, cols wc*128..+127, acc[4][8]. Grid 256 = 32mt x 2nt x
// 4ksp (1 block/CU). LDS 2 x (A 256x32 f32 32KB + B 256x32 bf16 16KB) =
// 96KB. A swizzle ch^=(row&7) (8 chunks), B ch^=(row&3) (4 chunks); both
// full-bankset b128 reads. Counted vmcnt(6): 6 DMA/thread/step.
__global__ __launch_bounds__(512) void k_gemm(const float* __restrict__ X,
                                              const unsigned short* __restrict__ Bt,
                                              unsigned short* __restrict__ P) {
  __shared__ __align__(16) char lds[2][49152];  // A f32 32KB | B bf16 16KB
  const int orig = blockIdx.x;
  const int wg = (orig & 7) * 32 + (orig >> 3);  // bijective (256%8==0)
  const int mt = wg >> 3;          // 0..31 (XCD keeps 4-mt band)
  const int nt = (wg >> 2) & 1;    // 0..1
  const int ksp = wg & 3;          // 0..3
  const int m0 = mt * 256, n0 = nt * 256, k0 = ksp * 512;
  const int t = threadIdx.x;
  const int wid = t >> 6, lane = t & 63;
  const int wr = wid >> 1, wc = wid & 1;  // wave: rows wr*64, cols wc*128

  f4 acc[4][8];
#pragma unroll
  for (int m = 0; m < 4; ++m)
#pragma unroll
    for (int n = 0; n < 8; ++n) acc[m][n] = f4{0.f, 0.f, 0.f, 0.f};

  // 6 gload_lds per thread per step: 4 A (f32) + 2 B (bf16).
  // A slot s=ii*512+t: row=s>>3, c8=s&7 -> src chunk c8^(row&7).
  // B slot s=ii*512+t: row=s>>2, c4=s&3 -> src chunk c4^(row&3).
#define ISSUE(BUF, KT)                                                     \
  do {                                                                     \
    const int kf = k0 + (KT) * 32;                                         \
    _Pragma("unroll") for (int ii = 0; ii < 4; ++ii) {                     \
      const int s = ii * 512 + t;                                          \
      const int row = s >> 3, c8 = s & 7;                                  \
      gload_lds16(X + (size_t)(m0 + row) * 2048 + kf +                     \
                      ((c8 ^ (row & 7)) << 2),                             \
                  &lds[BUF][ii * 8192 + wid * 1024]);                      \
    }                                                                      \
    _Pragma("unroll") for (int ii = 0; ii < 2; ++ii) {                     \
      const int s = ii * 512 + t;                                          \
      const int row = s >> 2, c4 = s & 3;                                  \
      gload_lds16(Bt + (size_t)(n0 + row) * 2048 + kf +                    \
                      ((c4 ^ (row & 3)) << 3),                             \
                  &lds[BUF][32768 + ii * 8192 + wid * 1024]);              \
    }                                                                      \
  } while (0)

  // per wave per step: 8 A-b128 (f32 lo/hi) + 16 cvt_pk + 8 B-b128 + 32 MFMA
#define COMPUTE(BUF)                                                       \
  do {                                                                     \
    const float* Ab = (const float*)&lds[BUF][0];                          \
    const unsigned short* Bb = (const unsigned short*)&lds[BUF][32768];    \
    short8 af[4], bfv[8];                                                  \
    const int q = lane >> 4;                                               \
    _Pragma("unroll") for (int m = 0; m < 4; ++m) {                        \
      const int row = wr * 64 + m * 16 + (lane & 15);                      \
      const int e = row & 7;                                               \
      f4 lo = *(const f4*)(Ab + row * 32 + (((2 * q) ^ e) << 2));          \
      f4 hi = *(const f4*)(Ab + row * 32 + (((2 * q + 1) ^ e) << 2));      \
      union { short8 s8; unsigned u[4]; } pk;                              \
      asm("v_cvt_pk_bf16_f32 %0, %1, %2" : "=v"(pk.u[0])                   \
          : "v"(lo[0]), "v"(lo[1]));                                       \
      asm("v_cvt_pk_bf16_f32 %0, %1, %2" : "=v"(pk.u[1])                   \
          : "v"(lo[2]), "v"(lo[3]));                                       \
      asm("v_cvt_pk_bf16_f32 %0, %1, %2" : "=v"(pk.u[2])                   \
          : "v"(hi[0]), "v"(hi[1]));                                       \
      asm("v_cvt_pk_bf16_f32 %0, %1, %2" : "=v"(pk.u[3])                   \
          : "v"(hi[2]), "v"(hi[3]));                                       \
      af[m] = pk.s8;                                                       \
    }                                                                      \
    _Pragma("unroll") for (int n = 0; n < 8; ++n) {                        \
      const int row = wc * 128 + n * 16 + (lane & 15);                     \
      bfv[n] = *(const short8*)((const unsigned short*)Bb + row * 32 +     \
                                ((q ^ (row & 3)) << 3));                   \
    }                                                                      \
    __builtin_amdgcn_s_setprio(1);                                         \
    _Pragma("unroll") for (int m = 0; m < 4; ++m)                          \
      _Pragma("unroll") for (int n = 0; n < 8; ++n)                        \
        acc[m][n] = __builtin_amdgcn_mfma_f32_16x16x32_bf16(               \
            af[m], bfv[n], acc[m][n], 0, 0, 0);                            \
    __builtin_amdgcn_s_setprio(0);                                         \
  } while (0)

  // prologue: steps 0,1 in flight (12 DMAs); wait step 0 (leave 6)
  ISSUE(0, 0);
  ISSUE(1, 1);
  __builtin_amdgcn_sched_barrier(0);
  asm volatile("s_waitcnt vmcnt(6)" ::: "memory");
  __builtin_amdgcn_s_barrier();
  __builtin_amdgcn_sched_barrier(0);

#pragma unroll 2
  for (int kt = 0; kt < 16; ++kt) {
    COMPUTE(kt & 1);
    __builtin_amdgcn_sched_barrier(0);
    __builtin_amdgcn_s_barrier();  // all waves done reading buf kt&1
    __builtin_amdgcn_sched_barrier(0);
    if (kt < 14) {
      ISSUE(kt & 1, kt + 2);       // 6 new; <=12 in flight
      __builtin_amdgcn_sched_barrier(0);
      asm volatile("s_waitcnt vmcnt(6)" ::: "memory");  // step kt+1 landed
      __builtin_amdgcn_s_barrier();
      __builtin_amdgcn_sched_barrier(0);
    } else if (kt == 14) {
      asm volatile("s_waitcnt vmcnt(0)" ::: "memory");  // step 15 landed
      __builtin_amdgcn_s_barrier();
      __builtin_amdgcn_sched_barrier(0);
    }
  }
#undef ISSUE
#undef COMPUTE

  // epilogue: partial write. C/D layout: col=lane&15, row=(lane>>4)*4+reg
  unsigned short* Pp = P + (size_t)ksp * (8192 * 512);
  const int mb = m0 + wr * 64, nb = n0 + wc * 128;
#pragma unroll
  for (int m = 0; m < 4; ++m)
#pragma unroll
    for (int n = 0; n < 8; ++n) {
      const int row0 = mb + m * 16 + ((lane >> 4) << 2);
      const int col = nb + n * 16 + (lane & 15);
#pragma unroll
      for (int r = 0; r < 4; ++r)
        Pp[(size_t)(row0 + r) * 512 + col] = f2bf(acc[m][n][r]);
    }
}

// ---- k_comb: h=gelu(sum_ksp(P0,P1)+bias); out = h@W2 + b2 ---------------
__global__ __launch_bounds__(256) void k_comb(const unsigned short* __restrict__ P,
                                              const unsigned short* __restrict__ W2t,
                                              const float* __restrict__ bias,
                                              const float* __restrict__ b2,
                                              float* __restrict__ out) {
  __shared__ unsigned short W2s[128 * 256];
  __shared__ unsigned short Hs[32 * 256];
  const int wg = blockIdx.x;
  const int b = wg >> 5, jt = wg & 31;
  const int j0 = jt * 32;
  const int t = threadIdx.x;

  {  // stage W2t
    const int row = t >> 1, halfc = (t & 1) * 128;
    const unsigned short* src = W2t + row * 256 + halfc;
    const int cbw = halfc >> 3;
#pragma unroll
    for (int i = 0; i < 16; ++i) {
      short8 v = *(const short8*)(src + i * 8);
      const int c = (cbw + i) ^ (row & 7);
      *(short8*)&W2s[row * 256 + c * 8] = v;
    }
  }
  {  // h rows
    const int r = t >> 3, seg = t & 7;
    const int j = j0 + r;
    const size_t m = (size_t)b * 1024 + j;
    const size_t mp1 = (j < 1023) ? m + 1 : m;
    const float* bs = bias + seg * 32;
    const int cbh = seg * 4;
#pragma unroll
    for (int i = 0; i < 4; ++i) {
      float f0[8];
#pragma unroll
      for (int q = 0; q < 8; ++q) f0[q] = bs[i * 8 + q];
#pragma unroll
      for (int ksp = 0; ksp < 4; ++ksp) {
        const unsigned short* Pk = P + (size_t)ksp * (8192 * 512);
        short8 v0 = *(const short8*)(Pk + m * 512 + seg * 32 + i * 8);
        short8 v1 = *(const short8*)(Pk + mp1 * 512 + 256 + seg * 32 + i * 8);
#pragma unroll
        for (int q = 0; q < 8; ++q)
          f0[q] += bf2f((unsigned short)v0[q]) + bf2f((unsigned short)v1[q]);
      }
      short8 pk;
#pragma unroll
      for (int q = 0; q < 8; ++q) {
        float g = 0.5f * f0[q] * (1.f + erff(f0[q] * 0.70710678118f));
        pk[q] = (short)f2bf(g);
      }
      const int c = (cbh + i) ^ (r & 7);
      *(short8*)&Hs[r * 256 + c * 8] = pk;
    }
  }
  __syncthreads();

  const int wid = t >> 6, lane = t & 63;
  f4 acc[2][2];
#pragma unroll
  for (int i = 0; i < 2; ++i)
#pragma unroll
    for (int j = 0; j < 2; ++j) acc[i][j] = f4{0.f, 0.f, 0.f, 0.f};

#pragma unroll
  for (int ks = 0; ks < 8; ++ks) {
    short8 af[2], bfr[2];
    const int cc = ks * 4 + (lane >> 4);
#pragma unroll
    for (int f = 0; f < 2; ++f) {
      const int ra = f * 16 + (lane & 15);
      af[f] = *(const short8*)&Hs[ra * 256 + ((cc ^ (ra & 7)) << 3)];
      const int rb = wid * 32 + f * 16 + (lane & 15);
      bfr[f] = *(const short8*)&W2s[rb * 256 + ((cc ^ (rb & 7)) << 3)];
    }
#pragma unroll
    for (int i = 0; i < 2; ++i)
#pragma unroll
      for (int j = 0; j < 2; ++j)
        acc[i][j] = __builtin_amdgcn_mfma_f32_16x16x32_bf16(af[i], bfr[j],
                                                            acc[i][j], 0, 0, 0);
  }
#pragma unroll
  for (int i = 0; i < 2; ++i)
#pragma unroll
    for (int j = 0; j < 2; ++j) {
      const int row0 = i * 16 + ((lane >> 4) << 2);
      const int col = wid * 32 + j * 16 + (lane & 15);
      const float bb = b2[col];
#pragma unroll
      for (int r = 0; r < 4; ++r) {
        const int jj = j0 + row0 + r;
        if (jj < 1023)
          out[((size_t)b * 1023 + jj) * 128 + col] = acc[i][j][r] + bb;
      }
    }
}

extern "C" void kernel_launch(void* const* d_in, const int* in_sizes, int n_in,
                              void* d_out, int out_size, void* d_ws, size_t ws_size,
                              hipStream_t stream) {
  const float* x   = (const float*)d_in[0];
  const float* pos = (const float*)d_in[1];
  const float* W1  = (const float*)d_in[2];
  const float* b1  = (const float*)d_in[3];
  const float* W2  = (const float*)d_in[4];
  const float* b2  = (const float*)d_in[5];
  float* out = (float*)d_out;
  char* ws = (char*)d_ws;
  unsigned short* Bt  = (unsigned short*)(ws + OFF_BT);
  unsigned short* W2t = (unsigned short*)(ws + OFF_W2T);
  float* part         = (float*)(ws + OFF_PART);
  float* bias         = (float*)(ws + OFF_BIAS);
  unsigned short* P   = (unsigned short*)(ws + OFF_P);

  k_prep<<<384, 256, 0, stream>>>(W1, pos, W2, Bt, W2t, part);
  k_bias<<<1, 256, 0, stream>>>(b1, part, bias);
  k_gemm<<<256, 512, 0, stream>>>(x, Bt, P);
  k_comb<<<256, 256, 0, stream>>>(P, W2t, bias, b2, out);
}

// Round 13
// 52.358 us; speedup vs baseline: 1.8339x; 1.1196x over previous
//
#include <hip/hip_runtime.h>
#include <hip/hip_bf16.h>
#include <math.h>

// TokenCompressor: B=8, N=16384, C=128, BLOCK=32, STRIDE=16 -> nb=1023
// Decomposition: chunks c of 16 tokens; A = x.view(8192, 2048) (contiguous!)
//   P[m, 0:256]  = chunk[m] @ W1[0:2048]
//   P[m, 256:512]= chunk[m] @ W1[2048:4096]
//   h[j] = gelu(P[j,0:256] + P[j+1,256:512] + b1 + posflat@W1)
//   out[j] = h[j] @ W2 + b2
// R13: consolidation. 12 structures bracket k_gemm at 40-52us; best TOTAL
// was R9 (53.9). This round: (1) R9 k_gemm + 3rd LDS buffer (144KB) ->
// prefetch covered by TWO compute phases (vmcnt(12) steady state) -- tests
// whether the residual step-wall is un-hidden L3 service latency; (2) k_bias
// folded into k_comb (one fewer launch); (3) everything else = R9 proven.

typedef __attribute__((ext_vector_type(8))) short short8;
typedef __attribute__((ext_vector_type(4))) float f4;

#define OFF_BT   0u                          // 512x2048 bf16 = 2 MB
#define OFF_W2T  (2u << 20)                  // 128x256 bf16 = 64 KB
#define OFF_PART ((2u << 20) + (64u << 10))  // 64x256 f32 = 64 KB
#define OFF_P    (4u << 20)                  // 8192x512 bf16 = 8 MB

static __device__ __forceinline__ unsigned short f2bf(float f) {
  union { float f; unsigned u; } v; v.f = f;
  return (unsigned short)((v.u + 0x7FFFu + ((v.u >> 16) & 1u)) >> 16);
}
static __device__ __forceinline__ float bf2f(unsigned short h) {
  union { unsigned u; float f; } v; v.u = ((unsigned)h) << 16;
  return v.f;
}
static __device__ __forceinline__ void gload_lds16(const void* g, void* l) {
  __builtin_amdgcn_global_load_lds(
      (const __attribute__((address_space(1))) void*)g,
      (__attribute__((address_space(3))) void*)l, 16, 0, 0);
}

// ---- k_prep: blocks 0..255: W1 -> Bt (512x2048 bf16, n-major) + bias parts
//              blocks 256..383: W2 (256x128 f32) -> W2t (128x256 bf16, T)
__global__ __launch_bounds__(256) void k_prep(const float* __restrict__ W1,
                                              const float* __restrict__ pos,
                                              const float* __restrict__ W2,
                                              unsigned short* __restrict__ Bt,
                                              unsigned short* __restrict__ W2t,
                                              float* __restrict__ part) {
  __shared__ float T[64][65];
  const int w = blockIdx.x;
  const int t = threadIdx.x;
  if (w >= 256) {
    const int n = w - 256;
    W2t[n * 256 + t] = f2bf(W2[t * 128 + n]);
    return;
  }
  const int h = w >> 7, rem = w & 127, kt = rem >> 2, nt = rem & 3;
  const int krow0 = h * 2048 + kt * 64, col0 = nt * 64;
  const int lr = t >> 2, lc = (t & 3) * 16;
  const float* src = W1 + (size_t)(krow0 + lr) * 256 + col0 + lc;
#pragma unroll
  for (int i = 0; i < 4; ++i) {
    f4 v = *(const f4*)(src + i * 4);
#pragma unroll
    for (int q = 0; q < 4; ++q) T[lr][lc + i * 4 + q] = v[q];
  }
  __syncthreads();
  if (t < 64) {
    float s = 0.f;
#pragma unroll 8
    for (int k = 0; k < 64; ++k) s += T[k][t] * pos[krow0 + k];
    part[(h * 32 + kt) * 256 + col0 + t] = s;
  }
  const int nl = t >> 2, kc = (t & 3) * 16;
  short8 o0, o1;
#pragma unroll
  for (int i = 0; i < 8; ++i) o0[i] = (short)f2bf(T[kc + i][nl]);
#pragma unroll
  for (int i = 0; i < 8; ++i) o1[i] = (short)f2bf(T[kc + 8 + i][nl]);
  unsigned short* dst = Bt + (size_t)(256 * h + col0 + nl) * 2048 + kt * 64 + kc;
  *(short8*)dst = o0;
  *(short8*)(dst + 8) = o1;
}

// ---- k_gemm: P (8192x512 bf16) = X(f32) @ Bt^T, full K=2048 -------------
// 128x128 tile, BK=64, 32 steps. 512 thr = 8 waves (4x2), per-wave 32x64
// (acc[2][4]). Grid 256 (1/CU). 3 LDS buffers x (A f32 32KB + B bf16 16KB)
// = 144KB: prefetch 2 steps ahead, steady-state vmcnt(12) -> each tile's
// DMA has ~2 compute phases to land. Swizzles identical to R9 (conflict-
// free, measured 0). f32->bf16 at fragment read (v_cvt_pk_bf16_f32).
__global__ __launch_bounds__(512) void k_gemm(const float* __restrict__ X,
                                              const unsigned short* __restrict__ Bt,
                                              unsigned short* __restrict__ P) {
  __shared__ __align__(16) char lds[3][49152];  // A f32 32KB | B bf16 16KB
  const int orig = blockIdx.x;
  const int wgid = (orig & 7) * 32 + (orig >> 3);  // bijective (256%8==0)
  const int mt = wgid >> 2, nt = wgid & 3;  // XCD keeps 8-mt band, all nt
  const int m0 = mt * 128, n0 = nt * 128;
  const int t = threadIdx.x;
  const int wid = t >> 6, lane = t & 63;
  const int wr = wid >> 1, wc = wid & 1;  // wave tile: rows wr*32, cols wc*64

  f4 acc[2][4];
#pragma unroll
  for (int m = 0; m < 2; ++m)
#pragma unroll
    for (int n = 0; n < 4; ++n) acc[m][n] = f4{0.f, 0.f, 0.f, 0.f};

  // 6 gload_lds per thread per tile: 4 A (f32) + 2 B (bf16).
  // A slot s=ii*512+t: row=s>>4, c16=s&15, src chunk = c16 ^ e(row),
  //   e = ((row&7)<<1)|((row>>3)&1) (full 16-chunk spread -> 32 banks).
  // B slot s=ii*512+t: row=s>>3, c8=s&7, src chunk = c8 ^ (row&7).
#define ISSUE(BUF, KT)                                                     \
  do {                                                                     \
    const int kf = (KT) * 64;                                              \
    _Pragma("unroll") for (int ii = 0; ii < 4; ++ii) {                     \
      const int s = ii * 512 + t;                                          \
      const int row = s >> 4, c16 = s & 15;                                \
      const int e = ((row & 7) << 1) | ((row >> 3) & 1);                   \
      gload_lds16(X + (size_t)(m0 + row) * 2048 + kf + ((c16 ^ e) << 2),   \
                  &lds[BUF][ii * 8192 + wid * 1024]);                      \
    }                                                                      \
    _Pragma("unroll") for (int ii = 0; ii < 2; ++ii) {                     \
      const int s = ii * 512 + t;                                          \
      const int row = s >> 3, c8 = s & 7;                                  \
      gload_lds16(Bt + (size_t)(n0 + row) * 2048 + kf +                    \
                      ((c8 ^ (row & 7)) << 3),                             \
                  &lds[BUF][32768 + ii * 8192 + wid * 1024]);              \
    }                                                                      \
  } while (0)

  // per wave per step: 8 A-b128 (f32 lo/hi) + 16 cvt_pk + 8 B-b128 + 16 MFMA
#define COMPUTE(BUF)                                                       \
  do {                                                                     \
    const float* Ab = (const float*)&lds[BUF][0];                          \
    const unsigned short* Bb = (const unsigned short*)&lds[BUF][32768];    \
    _Pragma("unroll") for (int ks = 0; ks < 2; ++ks) {                     \
      short8 af[2];                                                        \
      short8 bfv[4];                                                       \
      _Pragma("unroll") for (int m = 0; m < 2; ++m) {                      \
        const int row = wr * 32 + m * 16 + (lane & 15);                    \
        const int e = ((row & 7) << 1) | ((row >> 3) & 1);                 \
        const int cp = ks * 8 + (lane >> 4) * 2;                           \
        f4 lo = *(const f4*)(Ab + row * 64 + ((cp ^ e) << 2));             \
        f4 hi = *(const f4*)(Ab + row * 64 + (((cp + 1) ^ e) << 2));       \
        union { short8 s8; unsigned u[4]; } pk;                            \
        asm("v_cvt_pk_bf16_f32 %0, %1, %2" : "=v"(pk.u[0])                 \
            : "v"(lo[0]), "v"(lo[1]));                                     \
        asm("v_cvt_pk_bf16_f32 %0, %1, %2" : "=v"(pk.u[1])                 \
            : "v"(lo[2]), "v"(lo[3]));                                     \
        asm("v_cvt_pk_bf16_f32 %0, %1, %2" : "=v"(pk.u[2])                 \
            : "v"(hi[0]), "v"(hi[1]));                                     \
        asm("v_cvt_pk_bf16_f32 %0, %1, %2" : "=v"(pk.u[3])                 \
            : "v"(hi[2]), "v"(hi[3]));                                     \
        af[m] = pk.s8;                                                     \
      }                                                                    \
      _Pragma("unroll") for (int n = 0; n < 4; ++n) {                      \
        const int row = wc * 64 + n * 16 + (lane & 15);                    \
        const int ch = ks * 4 + (lane >> 4);                               \
        bfv[n] = *(const short8*)(Bb + row * 64 +                          \
                                  ((ch ^ (row & 7)) << 3));                \
      }                                                                    \
      __builtin_amdgcn_s_setprio(1);                                       \
      _Pragma("unroll") for (int m = 0; m < 2; ++m)                        \
        _Pragma("unroll") for (int n = 0; n < 4; ++n)                      \
          acc[m][n] = __builtin_amdgcn_mfma_f32_16x16x32_bf16(             \
              af[m], bfv[n], acc[m][n], 0, 0, 0);                          \
      __builtin_amdgcn_s_setprio(0);                                       \
    }                                                                      \
  } while (0)

  // prologue: tiles 0,1,2 in flight (18 DMAs); wait tile 0 (leave 12)
  ISSUE(0, 0);
  ISSUE(1, 1);
  ISSUE(2, 2);
  __builtin_amdgcn_sched_barrier(0);
  asm volatile("s_waitcnt vmcnt(12)" ::: "memory");
  __builtin_amdgcn_s_barrier();
  __builtin_amdgcn_sched_barrier(0);

  for (int kt = 0; kt < 32; ++kt) {
    COMPUTE(kt % 3);
    __builtin_amdgcn_sched_barrier(0);
    __builtin_amdgcn_s_barrier();  // all waves done reading buf kt%3
    __builtin_amdgcn_sched_barrier(0);
    if (kt < 29) {
      ISSUE(kt % 3, kt + 3);       // 6 new; tiles kt+2,kt+3 in flight (12)
      __builtin_amdgcn_sched_barrier(0);
      asm volatile("s_waitcnt vmcnt(12)" ::: "memory");  // tile kt+1 landed
      __builtin_amdgcn_s_barrier();
      __builtin_amdgcn_sched_barrier(0);
    } else if (kt == 29) {
      asm volatile("s_waitcnt vmcnt(6)" ::: "memory");   // tile 30 landed
      __builtin_amdgcn_s_barrier();
      __builtin_amdgcn_sched_barrier(0);
    } else if (kt == 30) {
      asm volatile("s_waitcnt vmcnt(0)" ::: "memory");   // tile 31 landed
      __builtin_amdgcn_s_barrier();
      __builtin_amdgcn_sched_barrier(0);
    }
  }
#undef ISSUE
#undef COMPUTE

  // epilogue: P bf16. C/D layout: col=lane&15, row=(lane>>4)*4+reg
  const int mb = m0 + wr * 32, nb = n0 + wc * 64;
#pragma unroll
  for (int m = 0; m < 2; ++m)
#pragma unroll
    for (int n = 0; n < 4; ++n) {
      const int row0 = mb + m * 16 + ((lane >> 4) << 2);
      const int col = nb + n * 16 + (lane & 15);
#pragma unroll
      for (int r = 0; r < 4; ++r)
        P[(size_t)(row0 + r) * 512 + col] = f2bf(acc[m][n][r]);
    }
}

// ---- k_comb: bias = b1 + reduce(part); h=gelu(P0+P1+bias); out=h@W2+b2 --
__global__ __launch_bounds__(256) void k_comb(const unsigned short* __restrict__ P,
                                              const unsigned short* __restrict__ W2t,
                                              const float* __restrict__ part,
                                              const float* __restrict__ b1,
                                              const float* __restrict__ b2,
                                              float* __restrict__ out) {
  __shared__ unsigned short W2s[128 * 256];
  __shared__ unsigned short Hs[32 * 256];
  __shared__ float biasS[256];
  const int wg = blockIdx.x;
  const int b = wg >> 5, jt = wg & 31;
  const int j0 = jt * 32;
  const int t = threadIdx.x;

  {  // bias reduction (replaces k_bias kernel): thread t owns column t
    float s = b1[t];
#pragma unroll 8
    for (int g = 0; g < 64; ++g) s += part[g * 256 + t];
    biasS[t] = s;
  }
  {  // stage W2t (rows 512B; swizzle slot ^= row&7)
    const int row = t >> 1, halfc = (t & 1) * 128;
    const unsigned short* src = W2t + row * 256 + halfc;
    const int cbw = halfc >> 3;
#pragma unroll
    for (int i = 0; i < 16; ++i) {
      short8 v = *(const short8*)(src + i * 8);
      const int c = (cbw + i) ^ (row & 7);
      *(short8*)&W2s[row * 256 + c * 8] = v;
    }
  }
  __syncthreads();
  {  // h rows: thread = (row r, 32-col segment)
    const int r = t >> 3, seg = t & 7;
    const int j = j0 + r;
    const size_t m = (size_t)b * 1024 + j;
    const size_t mp1 = (j < 1023) ? m + 1 : m;  // clamp (masked later)
    const unsigned short* p0 = P + m * 512 + seg * 32;
    const unsigned short* p1 = P + mp1 * 512 + 256 + seg * 32;
    const float* bs = biasS + seg * 32;
    const int cbh = seg * 4;
#pragma unroll
    for (int i = 0; i < 4; ++i) {
      short8 v0 = *(const short8*)(p0 + i * 8);
      short8 v1 = *(const short8*)(p1 + i * 8);
      short8 pk;
#pragma unroll
      for (int q = 0; q < 8; ++q) {
        float f = bf2f((unsigned short)v0[q]) + bf2f((unsigned short)v1[q]) +
                  bs[i * 8 + q];
        float g = 0.5f * f * (1.f + erff(f * 0.70710678118f));
        pk[q] = (short)f2bf(g);
      }
      const int c = (cbh + i) ^ (r & 7);
      *(short8*)&Hs[r * 256 + c * 8] = pk;
    }
  }
  __syncthreads();

  const int wid = t >> 6, lane = t & 63;
  f4 acc[2][2];
#pragma unroll
  for (int i = 0; i < 2; ++i)
#pragma unroll
    for (int j = 0; j < 2; ++j) acc[i][j] = f4{0.f, 0.f, 0.f, 0.f};

#pragma unroll
  for (int ks = 0; ks < 8; ++ks) {
    short8 af[2], bfr[2];
    const int cc = ks * 4 + (lane >> 4);
#pragma unroll
    for (int f = 0; f < 2; ++f) {
      const int ra = f * 16 + (lane & 15);
      af[f] = *(const short8*)&Hs[ra * 256 + ((cc ^ (ra & 7)) << 3)];
      const int rb = wid * 32 + f * 16 + (lane & 15);
      bfr[f] = *(const short8*)&W2s[rb * 256 + ((cc ^ (rb & 7)) << 3)];
    }
#pragma unroll
    for (int i = 0; i < 2; ++i)
#pragma unroll
      for (int j = 0; j < 2; ++j)
        acc[i][j] = __builtin_amdgcn_mfma_f32_16x16x32_bf16(af[i], bfr[j],
                                                            acc[i][j], 0, 0, 0);
  }
#pragma unroll
  for (int i = 0; i < 2; ++i)
#pragma unroll
    for (int j = 0; j < 2; ++j) {
      const int row0 = i * 16 + ((lane >> 4) << 2);
      const int col = wid * 32 + j * 16 + (lane & 15);
      const float bb = b2[col];
#pragma unroll
      for (int r = 0; r < 4; ++r) {
        const int jj = j0 + row0 + r;
        if (jj < 1023)
          out[((size_t)b * 1023 + jj) * 128 + col] = acc[i][j][r] + bb;
      }
    }
}

extern "C" void kernel_launch(void* const* d_in, const int* in_sizes, int n_in,
                              void* d_out, int out_size, void* d_ws, size_t ws_size,
                              hipStream_t stream) {
  const float* x   = (const float*)d_in[0];
  const float* pos = (const float*)d_in[1];
  const float* W1  = (const float*)d_in[2];
  const float* b1  = (const float*)d_in[3];
  const float* W2  = (const float*)d_in[4];
  const float* b2  = (const float*)d_in[5];
  float* out = (float*)d_out;
  char* ws = (char*)d_ws;
  unsigned short* Bt  = (unsigned short*)(ws + OFF_BT);
  unsigned short* W2t = (unsigned short*)(ws + OFF_W2T);
  float* part         = (float*)(ws + OFF_PART);
  unsigned short* P   = (unsigned short*)(ws + OFF_P);

  k_prep<<<384, 256, 0, stream>>>(W1, pos, W2, Bt, W2t, part);
  k_gemm<<<256, 512, 0, stream>>>(x, Bt, P);
  k_comb<<<256, 256, 0, stream>>>(P, W2t, part, b1, b2, out);
}

// Round 14
// 52.039 us; speedup vs baseline: 1.8451x; 1.0061x over previous
//
#include <hip/hip_runtime.h>
#include <hip/hip_bf16.h>
#include <math.h>

// TokenCompressor: B=8, N=16384, C=128, BLOCK=32, STRIDE=16 -> nb=1023
// Decomposition: chunks c of 16 tokens; A = x.view(8192, 2048) (contiguous!)
//   P[m, 0:256]  = chunk[m] @ W1[0:2048]
//   P[m, 256:512]= chunk[m] @ W1[2048:4096]
//   h[j] = gelu(P[j,0:256] + P[j+1,256:512] + b1 + posflat@W1)
//   out[j] = h[j] @ W2 + b2
// R14: k_gemm proven structurally plateaued (R9 1-deep = R13 2-deep = 42.5us;
// 13 structures bracket 40-52us = m102's measured wall for 2-barrier MFMA
// chassis at this shape). This round harvests non-gemm time: bias
// finalization folded into k_gemm's epilogue (kills k_comb's 16MB of
// redundant part re-reads); k_comb reads the finished 1KB bias vector.

typedef __attribute__((ext_vector_type(8))) short short8;
typedef __attribute__((ext_vector_type(4))) float f4;

#define OFF_BT   0u                          // 512x2048 bf16 = 2 MB
#define OFF_W2T  (2u << 20)                  // 128x256 bf16 = 64 KB
#define OFF_PART ((2u << 20) + (64u << 10))  // 64x256 f32 = 64 KB
#define OFF_BIAS ((2u << 20) + (128u << 10)) // 256 f32
#define OFF_P    (4u << 20)                  // 8192x512 bf16 = 8 MB

static __device__ __forceinline__ unsigned short f2bf(float f) {
  union { float f; unsigned u; } v; v.f = f;
  return (unsigned short)((v.u + 0x7FFFu + ((v.u >> 16) & 1u)) >> 16);
}
static __device__ __forceinline__ float bf2f(unsigned short h) {
  union { unsigned u; float f; } v; v.u = ((unsigned)h) << 16;
  return v.f;
}
static __device__ __forceinline__ void gload_lds16(const void* g, void* l) {
  __builtin_amdgcn_global_load_lds(
      (const __attribute__((address_space(1))) void*)g,
      (__attribute__((address_space(3))) void*)l, 16, 0, 0);
}

// ---- k_prep: blocks 0..255: W1 -> Bt (512x2048 bf16, n-major) + bias parts
//              blocks 256..383: W2 (256x128 f32) -> W2t (128x256 bf16, T)
__global__ __launch_bounds__(256) void k_prep(const float* __restrict__ W1,
                                              const float* __restrict__ pos,
                                              const float* __restrict__ W2,
                                              unsigned short* __restrict__ Bt,
                                              unsigned short* __restrict__ W2t,
                                              float* __restrict__ part) {
  __shared__ float T[64][65];
  const int w = blockIdx.x;
  const int t = threadIdx.x;
  if (w >= 256) {
    const int n = w - 256;
    W2t[n * 256 + t] = f2bf(W2[t * 128 + n]);
    return;
  }
  const int h = w >> 7, rem = w & 127, kt = rem >> 2, nt = rem & 3;
  const int krow0 = h * 2048 + kt * 64, col0 = nt * 64;
  const int lr = t >> 2, lc = (t & 3) * 16;
  const float* src = W1 + (size_t)(krow0 + lr) * 256 + col0 + lc;
#pragma unroll
  for (int i = 0; i < 4; ++i) {
    f4 v = *(const f4*)(src + i * 4);
#pragma unroll
    for (int q = 0; q < 4; ++q) T[lr][lc + i * 4 + q] = v[q];
  }
  __syncthreads();
  if (t < 64) {
    float s = 0.f;
#pragma unroll 8
    for (int k = 0; k < 64; ++k) s += T[k][t] * pos[krow0 + k];
    part[(h * 32 + kt) * 256 + col0 + t] = s;
  }
  const int nl = t >> 2, kc = (t & 3) * 16;
  short8 o0, o1;
#pragma unroll
  for (int i = 0; i < 8; ++i) o0[i] = (short)f2bf(T[kc + i][nl]);
#pragma unroll
  for (int i = 0; i < 8; ++i) o1[i] = (short)f2bf(T[kc + 8 + i][nl]);
  unsigned short* dst = Bt + (size_t)(256 * h + col0 + nl) * 2048 + kt * 64 + kc;
  *(short8*)dst = o0;
  *(short8*)(dst + 8) = o1;
}

// ---- k_gemm: P (8192x512 bf16) = X(f32) @ Bt^T, full K=2048 -------------
// 128x128 tile, BK=64, 32 steps. 512 thr = 8 waves (4x2), per-wave 32x64
// (acc[2][4]). Grid 256 (1/CU). 3 LDS buffers x (A f32 32KB + B bf16 16KB)
// = 144KB, prefetch 2 ahead, steady-state vmcnt(12). Epilogue additionally
// finalizes bias slice (b1 + reduce(part)) -- 64-way duplicate writes of
// bit-identical values, benign.
__global__ __launch_bounds__(512) void k_gemm(const float* __restrict__ X,
                                              const unsigned short* __restrict__ Bt,
                                              const float* __restrict__ part,
                                              const float* __restrict__ b1,
                                              float* __restrict__ biasG,
                                              unsigned short* __restrict__ P) {
  __shared__ __align__(16) char lds[3][49152];  // A f32 32KB | B bf16 16KB
  const int orig = blockIdx.x;
  const int wgid = (orig & 7) * 32 + (orig >> 3);  // bijective (256%8==0)
  const int mt = wgid >> 2, nt = wgid & 3;  // XCD keeps 8-mt band, all nt
  const int m0 = mt * 128, n0 = nt * 128;
  const int t = threadIdx.x;
  const int wid = t >> 6, lane = t & 63;
  const int wr = wid >> 1, wc = wid & 1;  // wave tile: rows wr*32, cols wc*64

  f4 acc[2][4];
#pragma unroll
  for (int m = 0; m < 2; ++m)
#pragma unroll
    for (int n = 0; n < 4; ++n) acc[m][n] = f4{0.f, 0.f, 0.f, 0.f};

  // 6 gload_lds per thread per tile: 4 A (f32) + 2 B (bf16).
  // A slot s=ii*512+t: row=s>>4, c16=s&15, src chunk = c16 ^ e(row),
  //   e = ((row&7)<<1)|((row>>3)&1) (full 16-chunk spread -> 32 banks).
  // B slot s=ii*512+t: row=s>>3, c8=s&7, src chunk = c8 ^ (row&7).
#define ISSUE(BUF, KT)                                                     \
  do {                                                                     \
    const int kf = (KT) * 64;                                              \
    _Pragma("unroll") for (int ii = 0; ii < 4; ++ii) {                     \
      const int s = ii * 512 + t;                                          \
      const int row = s >> 4, c16 = s & 15;                                \
      const int e = ((row & 7) << 1) | ((row >> 3) & 1);                   \
      gload_lds16(X + (size_t)(m0 + row) * 2048 + kf + ((c16 ^ e) << 2),   \
                  &lds[BUF][ii * 8192 + wid * 1024]);                      \
    }                                                                      \
    _Pragma("unroll") for (int ii = 0; ii < 2; ++ii) {                     \
      const int s = ii * 512 + t;                                          \
      const int row = s >> 3, c8 = s & 7;                                  \
      gload_lds16(Bt + (size_t)(n0 + row) * 2048 + kf +                    \
                      ((c8 ^ (row & 7)) << 3),                             \
                  &lds[BUF][32768 + ii * 8192 + wid * 1024]);              \
    }                                                                      \
  } while (0)

  // per wave per step: 8 A-b128 (f32 lo/hi) + 16 cvt_pk + 8 B-b128 + 16 MFMA
#define COMPUTE(BUF)                                                       \
  do {                                                                     \
    const float* Ab = (const float*)&lds[BUF][0];                          \
    const unsigned short* Bb = (const unsigned short*)&lds[BUF][32768];    \
    _Pragma("unroll") for (int ks = 0; ks < 2; ++ks) {                     \
      short8 af[2];                                                        \
      short8 bfv[4];                                                       \
      _Pragma("unroll") for (int m = 0; m < 2; ++m) {                      \
        const int row = wr * 32 + m * 16 + (lane & 15);                    \
        const int e = ((row & 7) << 1) | ((row >> 3) & 1);                 \
        const int cp = ks * 8 + (lane >> 4) * 2;                           \
        f4 lo = *(const f4*)(Ab + row * 64 + ((cp ^ e) << 2));             \
        f4 hi = *(const f4*)(Ab + row * 64 + (((cp + 1) ^ e) << 2));       \
        union { short8 s8; unsigned u[4]; } pk;                            \
        asm("v_cvt_pk_bf16_f32 %0, %1, %2" : "=v"(pk.u[0])                 \
            : "v"(lo[0]), "v"(lo[1]));                                     \
        asm("v_cvt_pk_bf16_f32 %0, %1, %2" : "=v"(pk.u[1])                 \
            : "v"(lo[2]), "v"(lo[3]));                                     \
        asm("v_cvt_pk_bf16_f32 %0, %1, %2" : "=v"(pk.u[2])                 \
            : "v"(hi[0]), "v"(hi[1]));                                     \
        asm("v_cvt_pk_bf16_f32 %0, %1, %2" : "=v"(pk.u[3])                 \
            : "v"(hi[2]), "v"(hi[3]));                                     \
        af[m] = pk.s8;                                                     \
      }                                                                    \
      _Pragma("unroll") for (int n = 0; n < 4; ++n) {                      \
        const int row = wc * 64 + n * 16 + (lane & 15);                    \
        const int ch = ks * 4 + (lane >> 4);                               \
        bfv[n] = *(const short8*)(Bb + row * 64 +                          \
                                  ((ch ^ (row & 7)) << 3));                \
      }                                                                    \
      __builtin_amdgcn_s_setprio(1);                                       \
      _Pragma("unroll") for (int m = 0; m < 2; ++m)                        \
        _Pragma("unroll") for (int n = 0; n < 4; ++n)                      \
          acc[m][n] = __builtin_amdgcn_mfma_f32_16x16x32_bf16(             \
              af[m], bfv[n], acc[m][n], 0, 0, 0);                          \
      __builtin_amdgcn_s_setprio(0);                                       \
    }                                                                      \
  } while (0)

  // prologue: tiles 0,1,2 in flight (18 DMAs); wait tile 0 (leave 12)
  ISSUE(0, 0);
  ISSUE(1, 1);
  ISSUE(2, 2);
  __builtin_amdgcn_sched_barrier(0);
  asm volatile("s_waitcnt vmcnt(12)" ::: "memory");
  __builtin_amdgcn_s_barrier();
  __builtin_amdgcn_sched_barrier(0);

  for (int kt = 0; kt < 32; ++kt) {
    COMPUTE(kt % 3);
    __builtin_amdgcn_sched_barrier(0);
    __builtin_amdgcn_s_barrier();  // all waves done reading buf kt%3
    __builtin_amdgcn_sched_barrier(0);
    if (kt < 29) {
      ISSUE(kt % 3, kt + 3);       // 6 new; tiles kt+2,kt+3 in flight (12)
      __builtin_amdgcn_sched_barrier(0);
      asm volatile("s_waitcnt vmcnt(12)" ::: "memory");  // tile kt+1 landed
      __builtin_amdgcn_s_barrier();
      __builtin_amdgcn_sched_barrier(0);
    } else if (kt == 29) {
      asm volatile("s_waitcnt vmcnt(6)" ::: "memory");   // tile 30 landed
      __builtin_amdgcn_s_barrier();
      __builtin_amdgcn_sched_barrier(0);
    } else if (kt == 30) {
      asm volatile("s_waitcnt vmcnt(0)" ::: "memory");   // tile 31 landed
      __builtin_amdgcn_s_barrier();
      __builtin_amdgcn_sched_barrier(0);
    }
  }
#undef ISSUE
#undef COMPUTE

  // epilogue A: bias slice (threads 0..127): bias[n] = b1[n] + sum_g part
  if (t < 128) {
    const int n = ((nt & 1) << 7) + t;
    float s = b1[n];
#pragma unroll 8
    for (int g = 0; g < 64; ++g) s += part[g * 256 + n];
    biasG[n] = s;
  }

  // epilogue B: P bf16. C/D layout: col=lane&15, row=(lane>>4)*4+reg
  const int mb = m0 + wr * 32, nb = n0 + wc * 64;
#pragma unroll
  for (int m = 0; m < 2; ++m)
#pragma unroll
    for (int n = 0; n < 4; ++n) {
      const int row0 = mb + m * 16 + ((lane >> 4) << 2);
      const int col = nb + n * 16 + (lane & 15);
#pragma unroll
      for (int r = 0; r < 4; ++r)
        P[(size_t)(row0 + r) * 512 + col] = f2bf(acc[m][n][r]);
    }
}

// ---- k_comb: h=gelu(P0+P1+bias); out = h@W2 + b2 -----------------------
__global__ __launch_bounds__(256) void k_comb(const unsigned short* __restrict__ P,
                                              const unsigned short* __restrict__ W2t,
                                              const float* __restrict__ biasG,
                                              const float* __restrict__ b2,
                                              float* __restrict__ out) {
  __shared__ unsigned short W2s[128 * 256];
  __shared__ unsigned short Hs[32 * 256];
  __shared__ float biasS[256];
  const int wg = blockIdx.x;
  const int b = wg >> 5, jt = wg & 31;
  const int j0 = jt * 32;
  const int t = threadIdx.x;

  biasS[t] = biasG[t];  // finished vector (k_gemm epilogue), 1KB
  {  // stage W2t (rows 512B; swizzle slot ^= row&7)
    const int row = t >> 1, halfc = (t & 1) * 128;
    const unsigned short* src = W2t + row * 256 + halfc;
    const int cbw = halfc >> 3;
#pragma unroll
    for (int i = 0; i < 16; ++i) {
      short8 v = *(const short8*)(src + i * 8);
      const int c = (cbw + i) ^ (row & 7);
      *(short8*)&W2s[row * 256 + c * 8] = v;
    }
  }
  __syncthreads();
  {  // h rows: thread = (row r, 32-col segment)
    const int r = t >> 3, seg = t & 7;
    const int j = j0 + r;
    const size_t m = (size_t)b * 1024 + j;
    const size_t mp1 = (j < 1023) ? m + 1 : m;  // clamp (masked later)
    const unsigned short* p0 = P + m * 512 + seg * 32;
    const unsigned short* p1 = P + mp1 * 512 + 256 + seg * 32;
    const float* bs = biasS + seg * 32;
    const int cbh = seg * 4;
#pragma unroll
    for (int i = 0; i < 4; ++i) {
      short8 v0 = *(const short8*)(p0 + i * 8);
      short8 v1 = *(const short8*)(p1 + i * 8);
      short8 pk;
#pragma unroll
      for (int q = 0; q < 8; ++q) {
        float f = bf2f((unsigned short)v0[q]) + bf2f((unsigned short)v1[q]) +
                  bs[i * 8 + q];
        float g = 0.5f * f * (1.f + erff(f * 0.70710678118f));
        pk[q] = (short)f2bf(g);
      }
      const int c = (cbh + i) ^ (r & 7);
      *(short8*)&Hs[r * 256 + c * 8] = pk;
    }
  }
  __syncthreads();

  const int wid = t >> 6, lane = t & 63;
  f4 acc[2][2];
#pragma unroll
  for (int i = 0; i < 2; ++i)
#pragma unroll
    for (int j = 0; j < 2; ++j) acc[i][j] = f4{0.f, 0.f, 0.f, 0.f};

#pragma unroll
  for (int ks = 0; ks < 8; ++ks) {
    short8 af[2], bfr[2];
    const int cc = ks * 4 + (lane >> 4);
#pragma unroll
    for (int f = 0; f < 2; ++f) {
      const int ra = f * 16 + (lane & 15);
      af[f] = *(const short8*)&Hs[ra * 256 + ((cc ^ (ra & 7)) << 3)];
      const int rb = wid * 32 + f * 16 + (lane & 15);
      bfr[f] = *(const short8*)&W2s[rb * 256 + ((cc ^ (rb & 7)) << 3)];
    }
#pragma unroll
    for (int i = 0; i < 2; ++i)
#pragma unroll
      for (int j = 0; j < 2; ++j)
        acc[i][j] = __builtin_amdgcn_mfma_f32_16x16x32_bf16(af[i], bfr[j],
                                                            acc[i][j], 0, 0, 0);
  }
#pragma unroll
  for (int i = 0; i < 2; ++i)
#pragma unroll
    for (int j = 0; j < 2; ++j) {
      const int row0 = i * 16 + ((lane >> 4) << 2);
      const int col = wid * 32 + j * 16 + (lane & 15);
      const float bb = b2[col];
#pragma unroll
      for (int r = 0; r < 4; ++r) {
        const int jj = j0 + row0 + r;
        if (jj < 1023)
          out[((size_t)b * 1023 + jj) * 128 + col] = acc[i][j][r] + bb;
      }
    }
}

extern "C" void kernel_launch(void* const* d_in, const int* in_sizes, int n_in,
                              void* d_out, int out_size, void* d_ws, size_t ws_size,
                              hipStream_t stream) {
  const float* x   = (const float*)d_in[0];
  const float* pos = (const float*)d_in[1];
  const float* W1  = (const float*)d_in[2];
  const float* b1  = (const float*)d_in[3];
  const float* W2  = (const float*)d_in[4];
  const float* b2  = (const float*)d_in[5];
  float* out = (float*)d_out;
  char* ws = (char*)d_ws;
  unsigned short* Bt  = (unsigned short*)(ws + OFF_BT);
  unsigned short* W2t = (unsigned short*)(ws + OFF_W2T);
  float* part         = (float*)(ws + OFF_PART);
  float* biasG        = (float*)(ws + OFF_BIAS);
  unsigned short* P   = (unsigned short*)(ws + OFF_P);

  k_prep<<<384, 256, 0, stream>>>(W1, pos, W2, Bt, W2t, part);
  k_gemm<<<256, 512, 0, stream>>>(x, Bt, part, b1, biasG, P);
  k_comb<<<256, 256, 0, stream>>>(P, W2t, biasG, b2, out);
}

// Round 15
// 49.381 us; speedup vs baseline: 1.9445x; 1.0538x over previous
//
#include <hip/hip_runtime.h>
#include <hip/hip_bf16.h>
#include <math.h>

// TokenCompressor: B=8, N=16384, C=128, BLOCK=32, STRIDE=16 -> nb=1023
// Decomposition: chunks c of 16 tokens; A = x.view(8192, 2048) (contiguous!)
//   P[m, 0:256]  = chunk[m] @ W1[0:2048]
//   P[m, 256:512]= chunk[m] @ W1[2048:4096]
//   h[j] = gelu(P[j,0:256] + P[j+1,256:512] + b1 + posflat@W1)
//   out[j] = h[j] @ W2 + b2
// R15: single-barrier steady state. R14's step had TWO 512-thread
// rendezvous (read-release, landing-confirm). With 3 buffers they merge:
// at step kt issue tile kt+2 into buf (kt+2)%3 == (kt-1)%3, whose readers
// were released by the PREVIOUS barrier; then one vmcnt(6)+s_barrier/step
// proves (a) all read tile kt, (b) tile kt+1 landed. 64 -> 33 barriers.
// Safety (verified per step): kt=0 ISSUE(2,2) fresh buf; COMPUTE(0) landed
// by prologue vmcnt(6); kt: COMPUTE(kt%3) landed by prev vmcnt(6)
// [outstanding then = tiles kt+1,kt+2 -> wait to 6 -> kt+1... shifts by one:
// at step kt the wait leaves tile kt+2's 6 in flight, tile kt+1 landed].

typedef __attribute__((ext_vector_type(8))) short short8;
typedef __attribute__((ext_vector_type(4))) float f4;

#define OFF_BT   0u                          // 512x2048 bf16 = 2 MB
#define OFF_W2T  (2u << 20)                  // 128x256 bf16 = 64 KB
#define OFF_PART ((2u << 20) + (64u << 10))  // 64x256 f32 = 64 KB
#define OFF_BIAS ((2u << 20) + (128u << 10)) // 256 f32
#define OFF_P    (4u << 20)                  // 8192x512 bf16 = 8 MB

static __device__ __forceinline__ unsigned short f2bf(float f) {
  union { float f; unsigned u; } v; v.f = f;
  return (unsigned short)((v.u + 0x7FFFu + ((v.u >> 16) & 1u)) >> 16);
}
static __device__ __forceinline__ float bf2f(unsigned short h) {
  union { unsigned u; float f; } v; v.u = ((unsigned)h) << 16;
  return v.f;
}
static __device__ __forceinline__ void gload_lds16(const void* g, void* l) {
  __builtin_amdgcn_global_load_lds(
      (const __attribute__((address_space(1))) void*)g,
      (__attribute__((address_space(3))) void*)l, 16, 0, 0);
}

// ---- k_prep: blocks 0..255: W1 -> Bt (512x2048 bf16, n-major) + bias parts
//              blocks 256..383: W2 (256x128 f32) -> W2t (128x256 bf16, T)
__global__ __launch_bounds__(256) void k_prep(const float* __restrict__ W1,
                                              const float* __restrict__ pos,
                                              const float* __restrict__ W2,
                                              unsigned short* __restrict__ Bt,
                                              unsigned short* __restrict__ W2t,
                                              float* __restrict__ part) {
  __shared__ float T[64][65];
  const int w = blockIdx.x;
  const int t = threadIdx.x;
  if (w >= 256) {
    const int n = w - 256;
    W2t[n * 256 + t] = f2bf(W2[t * 128 + n]);
    return;
  }
  const int h = w >> 7, rem = w & 127, kt = rem >> 2, nt = rem & 3;
  const int krow0 = h * 2048 + kt * 64, col0 = nt * 64;
  const int lr = t >> 2, lc = (t & 3) * 16;
  const float* src = W1 + (size_t)(krow0 + lr) * 256 + col0 + lc;
#pragma unroll
  for (int i = 0; i < 4; ++i) {
    f4 v = *(const f4*)(src + i * 4);
#pragma unroll
    for (int q = 0; q < 4; ++q) T[lr][lc + i * 4 + q] = v[q];
  }
  __syncthreads();
  if (t < 64) {
    float s = 0.f;
#pragma unroll 8
    for (int k = 0; k < 64; ++k) s += T[k][t] * pos[krow0 + k];
    part[(h * 32 + kt) * 256 + col0 + t] = s;
  }
  const int nl = t >> 2, kc = (t & 3) * 16;
  short8 o0, o1;
#pragma unroll
  for (int i = 0; i < 8; ++i) o0[i] = (short)f2bf(T[kc + i][nl]);
#pragma unroll
  for (int i = 0; i < 8; ++i) o1[i] = (short)f2bf(T[kc + 8 + i][nl]);
  unsigned short* dst = Bt + (size_t)(256 * h + col0 + nl) * 2048 + kt * 64 + kc;
  *(short8*)dst = o0;
  *(short8*)(dst + 8) = o1;
}

// ---- k_gemm: P (8192x512 bf16) = X(f32) @ Bt^T, full K=2048 -------------
// 128x128 tile, BK=64, 32 steps. 512 thr = 8 waves (4x2), per-wave 32x64
// (acc[2][4]). Grid 256 (1/CU). 3 LDS buffers x (A f32 32KB + B bf16 16KB)
// = 144KB. SINGLE barrier per step (see header). Epilogue finalizes bias.
__global__ __launch_bounds__(512) void k_gemm(const float* __restrict__ X,
                                              const unsigned short* __restrict__ Bt,
                                              const float* __restrict__ part,
                                              const float* __restrict__ b1,
                                              float* __restrict__ biasG,
                                              unsigned short* __restrict__ P) {
  __shared__ __align__(16) char lds[3][49152];  // A f32 32KB | B bf16 16KB
  const int orig = blockIdx.x;
  const int wgid = (orig & 7) * 32 + (orig >> 3);  // bijective (256%8==0)
  const int mt = wgid >> 2, nt = wgid & 3;  // XCD keeps 8-mt band, all nt
  const int m0 = mt * 128, n0 = nt * 128;
  const int t = threadIdx.x;
  const int wid = t >> 6, lane = t & 63;
  const int wr = wid >> 1, wc = wid & 1;  // wave tile: rows wr*32, cols wc*64

  f4 acc[2][4];
#pragma unroll
  for (int m = 0; m < 2; ++m)
#pragma unroll
    for (int n = 0; n < 4; ++n) acc[m][n] = f4{0.f, 0.f, 0.f, 0.f};

  // 6 gload_lds per thread per tile: 4 A (f32) + 2 B (bf16).
  // A slot s=ii*512+t: row=s>>4, c16=s&15, src chunk = c16 ^ e(row),
  //   e = ((row&7)<<1)|((row>>3)&1) (full 16-chunk spread -> 32 banks).
  // B slot s=ii*512+t: row=s>>3, c8=s&7, src chunk = c8 ^ (row&7).
#define ISSUE(BUF, KT)                                                     \
  do {                                                                     \
    const int kf = (KT) * 64;                                              \
    _Pragma("unroll") for (int ii = 0; ii < 4; ++ii) {                     \
      const int s = ii * 512 + t;                                          \
      const int row = s >> 4, c16 = s & 15;                                \
      const int e = ((row & 7) << 1) | ((row >> 3) & 1);                   \
      gload_lds16(X + (size_t)(m0 + row) * 2048 + kf + ((c16 ^ e) << 2),   \
                  &lds[BUF][ii * 8192 + wid * 1024]);                      \
    }                                                                      \
    _Pragma("unroll") for (int ii = 0; ii < 2; ++ii) {                     \
      const int s = ii * 512 + t;                                          \
      const int row = s >> 3, c8 = s & 7;                                  \
      gload_lds16(Bt + (size_t)(n0 + row) * 2048 + kf +                    \
                      ((c8 ^ (row & 7)) << 3),                             \
                  &lds[BUF][32768 + ii * 8192 + wid * 1024]);              \
    }                                                                      \
  } while (0)

  // per wave per step: 8 A-b128 (f32 lo/hi) + 16 cvt_pk + 8 B-b128 + 16 MFMA
#define COMPUTE(BUF)                                                       \
  do {                                                                     \
    const float* Ab = (const float*)&lds[BUF][0];                          \
    const unsigned short* Bb = (const unsigned short*)&lds[BUF][32768];    \
    _Pragma("unroll") for (int ks = 0; ks < 2; ++ks) {                     \
      short8 af[2];                                                        \
      short8 bfv[4];                                                       \
      _Pragma("unroll") for (int m = 0; m < 2; ++m) {                      \
        const int row = wr * 32 + m * 16 + (lane & 15);                    \
        const int e = ((row & 7) << 1) | ((row >> 3) & 1);                 \
        const int cp = ks * 8 + (lane >> 4) * 2;                           \
        f4 lo = *(const f4*)(Ab + row * 64 + ((cp ^ e) << 2));             \
        f4 hi = *(const f4*)(Ab + row * 64 + (((cp + 1) ^ e) << 2));       \
        union { short8 s8; unsigned u[4]; } pk;                            \
        asm("v_cvt_pk_bf16_f32 %0, %1, %2" : "=v"(pk.u[0])                 \
            : "v"(lo[0]), "v"(lo[1]));                                     \
        asm("v_cvt_pk_bf16_f32 %0, %1, %2" : "=v"(pk.u[1])                 \
            : "v"(lo[2]), "v"(lo[3]));                                     \
        asm("v_cvt_pk_bf16_f32 %0, %1, %2" : "=v"(pk.u[2])                 \
            : "v"(hi[0]), "v"(hi[1]));                                     \
        asm("v_cvt_pk_bf16_f32 %0, %1, %2" : "=v"(pk.u[3])                 \
            : "v"(hi[2]), "v"(hi[3]));                                     \
        af[m] = pk.s8;                                                     \
      }                                                                    \
      _Pragma("unroll") for (int n = 0; n < 4; ++n) {                      \
        const int row = wc * 64 + n * 16 + (lane & 15);                    \
        const int ch = ks * 4 + (lane >> 4);                               \
        bfv[n] = *(const short8*)(Bb + row * 64 +                          \
                                  ((ch ^ (row & 7)) << 3));                \
      }                                                                    \
      __builtin_amdgcn_s_setprio(1);                                       \
      _Pragma("unroll") for (int m = 0; m < 2; ++m)                        \
        _Pragma("unroll") for (int n = 0; n < 4; ++n)                      \
          acc[m][n] = __builtin_amdgcn_mfma_f32_16x16x32_bf16(             \
              af[m], bfv[n], acc[m][n], 0, 0, 0);                          \
      __builtin_amdgcn_s_setprio(0);                                       \
    }                                                                      \
  } while (0)

  // prologue: tiles 0,1 in flight (12 DMAs); wait tile 0 (leave 6)
  ISSUE(0, 0);
  ISSUE(1, 1);
  __builtin_amdgcn_sched_barrier(0);
  asm volatile("s_waitcnt vmcnt(6)" ::: "memory");
  __builtin_amdgcn_s_barrier();
  __builtin_amdgcn_sched_barrier(0);

  // single-barrier steady state:
  //   step kt: ISSUE((kt+2)%3, kt+2)  [buf released by barrier kt-1]
  //            COMPUTE(kt%3)          [tile kt landed: proven at barrier kt-1]
  //            vmcnt(6)+barrier       [tile kt+1 landed; readers of kt done]
  for (int kt = 0; kt < 32; ++kt) {
    if (kt < 30) ISSUE((kt + 2) % 3, kt + 2);
    COMPUTE(kt % 3);
    __builtin_amdgcn_sched_barrier(0);
    if (kt < 31) {
      if (kt < 30) asm volatile("s_waitcnt vmcnt(6)" ::: "memory");
      else         asm volatile("s_waitcnt vmcnt(0)" ::: "memory");
      __builtin_amdgcn_s_barrier();
      __builtin_amdgcn_sched_barrier(0);
    }
  }
#undef ISSUE
#undef COMPUTE

  // epilogue A: bias slice (threads 0..127): bias[n] = b1[n] + sum_g part
  if (t < 128) {
    const int n = ((nt & 1) << 7) + t;
    float s = b1[n];
#pragma unroll 8
    for (int g = 0; g < 64; ++g) s += part[g * 256 + n];
    biasG[n] = s;
  }

  // epilogue B: P bf16. C/D layout: col=lane&15, row=(lane>>4)*4+reg
  const int mb = m0 + wr * 32, nb = n0 + wc * 64;
#pragma unroll
  for (int m = 0; m < 2; ++m)
#pragma unroll
    for (int n = 0; n < 4; ++n) {
      const int row0 = mb + m * 16 + ((lane >> 4) << 2);
      const int col = nb + n * 16 + (lane & 15);
#pragma unroll
      for (int r = 0; r < 4; ++r)
        P[(size_t)(row0 + r) * 512 + col] = f2bf(acc[m][n][r]);
    }
}

// ---- k_comb: h=gelu(P0+P1+bias); out = h@W2 + b2 -----------------------
__global__ __launch_bounds__(256) void k_comb(const unsigned short* __restrict__ P,
                                              const unsigned short* __restrict__ W2t,
                                              const float* __restrict__ biasG,
                                              const float* __restrict__ b2,
                                              float* __restrict__ out) {
  __shared__ unsigned short W2s[128 * 256];
  __shared__ unsigned short Hs[32 * 256];
  __shared__ float biasS[256];
  const int wg = blockIdx.x;
  const int b = wg >> 5, jt = wg & 31;
  const int j0 = jt * 32;
  const int t = threadIdx.x;

  biasS[t] = biasG[t];  // finished vector (k_gemm epilogue), 1KB
  {  // stage W2t (rows 512B; swizzle slot ^= row&7)
    const int row = t >> 1, halfc = (t & 1) * 128;
    const unsigned short* src = W2t + row * 256 + halfc;
    const int cbw = halfc >> 3;
#pragma unroll
    for (int i = 0; i < 16; ++i) {
      short8 v = *(const short8*)(src + i * 8);
      const int c = (cbw + i) ^ (row & 7);
      *(short8*)&W2s[row * 256 + c * 8] = v;
    }
  }
  __syncthreads();
  {  // h rows: thread = (row r, 32-col segment)
    const int r = t >> 3, seg = t & 7;
    const int j = j0 + r;
    const size_t m = (size_t)b * 1024 + j;
    const size_t mp1 = (j < 1023) ? m + 1 : m;  // clamp (masked later)
    const unsigned short* p0 = P + m * 512 + seg * 32;
    const unsigned short* p1 = P + mp1 * 512 + 256 + seg * 32;
    const float* bs = biasS + seg * 32;
    const int cbh = seg * 4;
#pragma unroll
    for (int i = 0; i < 4; ++i) {
      short8 v0 = *(const short8*)(p0 + i * 8);
      short8 v1 = *(const short8*)(p1 + i * 8);
      short8 pk;
#pragma unroll
      for (int q = 0; q < 8; ++q) {
        float f = bf2f((unsigned short)v0[q]) + bf2f((unsigned short)v1[q]) +
                  bs[i * 8 + q];
        float g = 0.5f * f * (1.f + erff(f * 0.70710678118f));
        pk[q] = (short)f2bf(g);
      }
      const int c = (cbh + i) ^ (r & 7);
      *(short8*)&Hs[r * 256 + c * 8] = pk;
    }
  }
  __syncthreads();

  const int wid = t >> 6, lane = t & 63;
  f4 acc[2][2];
#pragma unroll
  for (int i = 0; i < 2; ++i)
#pragma unroll
    for (int j = 0; j < 2; ++j) acc[i][j] = f4{0.f, 0.f, 0.f, 0.f};

#pragma unroll
  for (int ks = 0; ks < 8; ++ks) {
    short8 af[2], bfr[2];
    const int cc = ks * 4 + (lane >> 4);
#pragma unroll
    for (int f = 0; f < 2; ++f) {
      const int ra = f * 16 + (lane & 15);
      af[f] = *(const short8*)&Hs[ra * 256 + ((cc ^ (ra & 7)) << 3)];
      const int rb = wid * 32 + f * 16 + (lane & 15);
      bfr[f] = *(const short8*)&W2s[rb * 256 + ((cc ^ (rb & 7)) << 3)];
    }
#pragma unroll
    for (int i = 0; i < 2; ++i)
#pragma unroll
      for (int j = 0; j < 2; ++j)
        acc[i][j] = __builtin_amdgcn_mfma_f32_16x16x32_bf16(af[i], bfr[j],
                                                            acc[i][j], 0, 0, 0);
  }
#pragma unroll
  for (int i = 0; i < 2; ++i)
#pragma unroll
    for (int j = 0; j < 2; ++j) {
      const int row0 = i * 16 + ((lane >> 4) << 2);
      const int col = wid * 32 + j * 16 + (lane & 15);
      const float bb = b2[col];
#pragma unroll
      for (int r = 0; r < 4; ++r) {
        const int jj = j0 + row0 + r;
        if (jj < 1023)
          out[((size_t)b * 1023 + jj) * 128 + col] = acc[i][j][r] + bb;
      }
    }
}

extern "C" void kernel_launch(void* const* d_in, const int* in_sizes, int n_in,
                              void* d_out, int out_size, void* d_ws, size_t ws_size,
                              hipStream_t stream) {
  const float* x   = (const float*)d_in[0];
  const float* pos = (const float*)d_in[1];
  const float* W1  = (const float*)d_in[2];
  const float* b1  = (const float*)d_in[3];
  const float* W2  = (const float*)d_in[4];
  const float* b2  = (const float*)d_in[5];
  float* out = (float*)d_out;
  char* ws = (char*)d_ws;
  unsigned short* Bt  = (unsigned short*)(ws + OFF_BT);
  unsigned short* W2t = (unsigned short*)(ws + OFF_W2T);
  float* part         = (float*)(ws + OFF_PART);
  float* biasG        = (float*)(ws + OFF_BIAS);
  unsigned short* P   = (unsigned short*)(ws + OFF_P);

  k_prep<<<384, 256, 0, stream>>>(W1, pos, W2, Bt, W2t, part);
  k_gemm<<<256, 512, 0, stream>>>(x, Bt, part, b1, biasG, P);
  k_comb<<<256, 256, 0, stream>>>(P, W2t, biasG, b2, out);
}